// Round 3
// baseline (109.456 us; speedup 1.0000x reference)
//
#include <hip/hip_runtime.h>

// Damped electrostatics with shifted-force cutoff.
// 4 edges per thread: vectorized streaming loads (ext_vector float4/int4,
// non-temporal) + batched gathers for memory-level parallelism.

#define CUTOFF      10.0f
#define KEHALF      7.199822675975274f
#define OFFSET2     1.0f

typedef float f32x4 __attribute__((ext_vector_type(4)));
typedef int   i32x4 __attribute__((ext_vector_type(4)));

__device__ __forceinline__ float edge_energy(
    float d, float vx, float vy, float vz,
    float qu, float qv,
    float du0, float du1, float du2,
    float dv0, float dv1, float dv2,
    float q00, float q01, float q02,
    float q10, float q11, float q12,
    float q20, float q21, float q22)
{
    float inv_d = 1.0f / d;
    float d_damped = sqrtf(d * d + OFFSET2);

    // poly5 switch, cutoff_sr = 4
    float x = d * 0.25f;
    float x2 = x * x;
    float x3 = x2 * x;
    float sw = 1.0f - x3 * (10.0f - 15.0f * x + 6.0f * x2);
    sw = (x < 1.0f) ? sw : 0.0f;
    float chi = sw / d_damped + (1.0f - sw) * inv_d;

    // shifted-force corrections (cutoff = 10)
    float c1 = chi - (0.2f   - 0.01f   * d);
    float chi2 = chi * chi;
    float chi3 = chi2 * chi;
    float c2 = chi2 - (0.03f  - 0.002f  * d);
    float c3 = chi3 - (0.004f - 0.0003f * d);

    float Ee = qu * qv * c1;

    float dot_uv = (vx * dv0 + vy * dv1 + vz * dv2) * inv_d;
    float dot_vu = (vx * du0 + vy * du1 + vz * du2) * inv_d;
    float dd     = du0 * dv0 + du1 * dv1 + du2 * dv2;

    Ee += 2.0f * qu * dot_uv * c2;
    Ee += (dd - 3.0f * dot_uv * dot_vu) * c3;

    // quadrupole: v^T Q v / d^2 - tr(Q)/3   (|v| == d)
    float vQv = vx * (q00 * vx + q01 * vy + q02 * vz)
              + vy * (q10 * vx + q11 * vy + q12 * vz)
              + vz * (q20 * vx + q21 * vy + q22 * vz);
    float trQ = q00 + q11 + q22;
    float sum_uv = vQv * inv_d * inv_d - trQ * (1.0f / 3.0f);

    Ee += qu * sum_uv * c3;

    Ee *= KEHALF;
    return (d <= CUTOFF) ? Ee : 0.0f;
}

__global__ __launch_bounds__(256) void damped_elec_kernel4(
    const float* __restrict__ q,      // [N]
    const float* __restrict__ dip,    // [N,3]
    const float* __restrict__ quad,   // [N,9]
    const float* __restrict__ vec,    // [E,3]
    const float* __restrict__ dist,   // [E]
    const int*   __restrict__ idx_u,  // [E]
    const int*   __restrict__ idx_v,  // [E]
    float*       __restrict__ out,    // [E]
    int E)
{
    int t = blockIdx.x * blockDim.x + threadIdx.x;
    size_t base = 4 * (size_t)t;

    if (base + 3 < (size_t)E) {
        // ---- streaming loads (non-temporal: keep L2 for the atom tables) ----
        const f32x4* vp = (const f32x4*)(vec + 3 * base);
        f32x4 v0 = __builtin_nontemporal_load(vp + 0);
        f32x4 v1 = __builtin_nontemporal_load(vp + 1);
        f32x4 v2 = __builtin_nontemporal_load(vp + 2);
        f32x4 d4 = __builtin_nontemporal_load((const f32x4*)(dist + base));
        i32x4 u4 = __builtin_nontemporal_load((const i32x4*)(idx_u + base));
        i32x4 w4 = __builtin_nontemporal_load((const i32x4*)(idx_v + base));

        float ds[4]  = {d4.x, d4.y, d4.z, d4.w};
        float vxs[4] = {v0.x, v0.w, v1.z, v2.y};
        float vys[4] = {v0.y, v1.x, v1.w, v2.z};
        float vzs[4] = {v0.z, v1.y, v2.x, v2.w};
        int   us[4]  = {u4.x, u4.y, u4.z, u4.w};
        int   vs[4]  = {w4.x, w4.y, w4.z, w4.w};

        // ---- batched gathers: issue all loads before any compute ----
        float qus[4], qvs[4];
        float du[4][3], dv[4][3];
        float Q[4][9];
#pragma unroll
        for (int e = 0; e < 4; ++e) {
            qus[e] = q[us[e]];
            qvs[e] = q[vs[e]];
        }
#pragma unroll
        for (int e = 0; e < 4; ++e) {
            const float* pu = dip + 3 * (size_t)us[e];
            const float* pv = dip + 3 * (size_t)vs[e];
            du[e][0] = pu[0]; du[e][1] = pu[1]; du[e][2] = pu[2];
            dv[e][0] = pv[0]; dv[e][1] = pv[1]; dv[e][2] = pv[2];
        }
#pragma unroll
        for (int e = 0; e < 4; ++e) {
            const float* pq = quad + 9 * (size_t)vs[e];
#pragma unroll
            for (int k = 0; k < 9; ++k) Q[e][k] = pq[k];
        }

        float r[4];
#pragma unroll
        for (int e = 0; e < 4; ++e) {
            r[e] = edge_energy(ds[e], vxs[e], vys[e], vzs[e],
                               qus[e], qvs[e],
                               du[e][0], du[e][1], du[e][2],
                               dv[e][0], dv[e][1], dv[e][2],
                               Q[e][0], Q[e][1], Q[e][2],
                               Q[e][3], Q[e][4], Q[e][5],
                               Q[e][6], Q[e][7], Q[e][8]);
        }
        f32x4 res = {r[0], r[1], r[2], r[3]};
        __builtin_nontemporal_store(res, (f32x4*)(out + base));
    } else {
        // tail: scalar
        for (size_t i = base; i < (size_t)E; ++i) {
            float d  = dist[i];
            float vx = vec[3 * i + 0];
            float vy = vec[3 * i + 1];
            float vz = vec[3 * i + 2];
            int u = idx_u[i];
            int v = idx_v[i];
            const float* pu = dip + 3 * (size_t)u;
            const float* pv = dip + 3 * (size_t)v;
            const float* pq = quad + 9 * (size_t)v;
            out[i] = edge_energy(d, vx, vy, vz, q[u], q[v],
                                 pu[0], pu[1], pu[2],
                                 pv[0], pv[1], pv[2],
                                 pq[0], pq[1], pq[2],
                                 pq[3], pq[4], pq[5],
                                 pq[6], pq[7], pq[8]);
        }
    }
}

extern "C" void kernel_launch(void* const* d_in, const int* in_sizes, int n_in,
                              void* d_out, int out_size, void* d_ws, size_t ws_size,
                              hipStream_t stream) {
    const float* q    = (const float*)d_in[0];  // atomic_charges      [N]
    const float* dip  = (const float*)d_in[1];  // atomic_dipoles      [N,3]
    const float* quad = (const float*)d_in[2];  // atomic_quadrupoles  [N,3,3]
    const float* vec  = (const float*)d_in[3];  // vectors_uv          [E,3]
    const float* dist = (const float*)d_in[4];  // distances_uv        [E]
    const int*   iu   = (const int*)d_in[5];    // idx_u               [E]
    const int*   iv   = (const int*)d_in[6];    // idx_v               [E]
    float* out = (float*)d_out;

    int E = in_sizes[4];
    int nthreads = (E + 3) / 4;
    int block = 256;
    int grid = (nthreads + block - 1) / block;
    damped_elec_kernel4<<<grid, block, 0, stream>>>(q, dip, quad, vec, dist, iu, iv, out, E);
}

// Round 4
// 83.033 us; speedup vs baseline: 1.3182x; 1.3182x over previous
//
#include <hip/hip_runtime.h>

// Damped electrostatics with shifted-force cutoff.
// Pre-pass packs per-atom (charge, dipole, quadrupole) into one 64B
// cache-line-aligned record in d_ws; edge kernel then does exactly
// 5 divergent dwordx4 gathers touching 2 unique lines per edge.

#define CUTOFF      10.0f
#define KEHALF      7.199822675975274f
#define OFFSET2     1.0f

typedef float f32x4 __attribute__((ext_vector_type(4)));

__device__ __forceinline__ float edge_energy(
    float d, float vx, float vy, float vz,
    float qu, float qv,
    float du0, float du1, float du2,
    float dv0, float dv1, float dv2,
    float q00, float q01, float q02,
    float q10, float q11, float q12,
    float q20, float q21, float q22)
{
    float inv_d = 1.0f / d;
    float d_damped = sqrtf(d * d + OFFSET2);

    // poly5 switch, cutoff_sr = 4
    float x = d * 0.25f;
    float x2 = x * x;
    float x3 = x2 * x;
    float sw = 1.0f - x3 * (10.0f - 15.0f * x + 6.0f * x2);
    sw = (x < 1.0f) ? sw : 0.0f;
    float chi = sw / d_damped + (1.0f - sw) * inv_d;

    // shifted-force corrections (cutoff = 10)
    float c1 = chi - (0.2f   - 0.01f   * d);
    float chi2 = chi * chi;
    float chi3 = chi2 * chi;
    float c2 = chi2 - (0.03f  - 0.002f  * d);
    float c3 = chi3 - (0.004f - 0.0003f * d);

    float Ee = qu * qv * c1;

    float dot_uv = (vx * dv0 + vy * dv1 + vz * dv2) * inv_d;
    float dot_vu = (vx * du0 + vy * du1 + vz * du2) * inv_d;
    float dd     = du0 * dv0 + du1 * dv1 + du2 * dv2;

    Ee += 2.0f * qu * dot_uv * c2;
    Ee += (dd - 3.0f * dot_uv * dot_vu) * c3;

    // quadrupole: v^T Q v / d^2 - tr(Q)/3   (|v| == d)
    float vQv = vx * (q00 * vx + q01 * vy + q02 * vz)
              + vy * (q10 * vx + q11 * vy + q12 * vz)
              + vz * (q20 * vx + q21 * vy + q22 * vz);
    float trQ = q00 + q11 + q22;
    float sum_uv = vQv * inv_d * inv_d - trQ * (1.0f / 3.0f);

    Ee += qu * sum_uv * c3;

    Ee *= KEHALF;
    return (d <= CUTOFF) ? Ee : 0.0f;
}

// Pack atom i into 64B: [q, dx, dy, dz | q00,q01,q02,q10 | q11,q12,q20,q21 | q22,0,0,0]
__global__ __launch_bounds__(256) void pack_atoms_kernel(
    const float* __restrict__ q,
    const float* __restrict__ dip,
    const float* __restrict__ quad,
    float* __restrict__ packed,
    int N)
{
    int i = blockIdx.x * blockDim.x + threadIdx.x;
    if (i >= N) return;
    const float* dp = dip + 3 * (size_t)i;
    const float* qp = quad + 9 * (size_t)i;
    f32x4 w0 = {q[i],  dp[0], dp[1], dp[2]};
    f32x4 w1 = {qp[0], qp[1], qp[2], qp[3]};
    f32x4 w2 = {qp[4], qp[5], qp[6], qp[7]};
    f32x4 w3 = {qp[8], 0.0f,  0.0f,  0.0f};
    f32x4* dst = (f32x4*)packed + 4 * (size_t)i;
    dst[0] = w0; dst[1] = w1; dst[2] = w2; dst[3] = w3;
}

__global__ __launch_bounds__(256) void damped_elec_packed(
    const float* __restrict__ packed, // [N,16] (64B records)
    const float* __restrict__ vec,    // [E,3]
    const float* __restrict__ dist,   // [E]
    const int*   __restrict__ idx_u,  // [E]
    const int*   __restrict__ idx_v,  // [E]
    float*       __restrict__ out,    // [E]
    int E)
{
    int i = blockIdx.x * blockDim.x + threadIdx.x;
    if (i >= E) return;

    float d  = dist[i];
    float vx = vec[3 * (size_t)i + 0];
    float vy = vec[3 * (size_t)i + 1];
    float vz = vec[3 * (size_t)i + 2];
    int u = idx_u[i];
    int v = idx_v[i];

    const f32x4* P = (const f32x4*)packed;
    f32x4 au = P[4 * (size_t)u];       // q_u, dip_u       (1 line)
    f32x4 b0 = P[4 * (size_t)v + 0];   // q_v, dip_v       (same line as b1-b3)
    f32x4 b1 = P[4 * (size_t)v + 1];
    f32x4 b2 = P[4 * (size_t)v + 2];
    f32x4 b3 = P[4 * (size_t)v + 3];

    out[i] = edge_energy(d, vx, vy, vz,
                         au.x, b0.x,
                         au.y, au.z, au.w,
                         b0.y, b0.z, b0.w,
                         b1.x, b1.y, b1.z,
                         b1.w, b2.x, b2.y,
                         b2.z, b2.w, b3.x);
}

// Fallback if ws_size is too small for the packed table.
__global__ __launch_bounds__(256) void damped_elec_unpacked(
    const float* __restrict__ q,
    const float* __restrict__ dip,
    const float* __restrict__ quad,
    const float* __restrict__ vec,
    const float* __restrict__ dist,
    const int*   __restrict__ idx_u,
    const int*   __restrict__ idx_v,
    float*       __restrict__ out,
    int E)
{
    int i = blockIdx.x * blockDim.x + threadIdx.x;
    if (i >= E) return;
    float d  = dist[i];
    float vx = vec[3 * (size_t)i + 0];
    float vy = vec[3 * (size_t)i + 1];
    float vz = vec[3 * (size_t)i + 2];
    int u = idx_u[i];
    int v = idx_v[i];
    const float* pu = dip + 3 * (size_t)u;
    const float* pv = dip + 3 * (size_t)v;
    const float* pq = quad + 9 * (size_t)v;
    out[i] = edge_energy(d, vx, vy, vz, q[u], q[v],
                         pu[0], pu[1], pu[2],
                         pv[0], pv[1], pv[2],
                         pq[0], pq[1], pq[2],
                         pq[3], pq[4], pq[5],
                         pq[6], pq[7], pq[8]);
}

extern "C" void kernel_launch(void* const* d_in, const int* in_sizes, int n_in,
                              void* d_out, int out_size, void* d_ws, size_t ws_size,
                              hipStream_t stream) {
    const float* q    = (const float*)d_in[0];  // atomic_charges      [N]
    const float* dip  = (const float*)d_in[1];  // atomic_dipoles      [N,3]
    const float* quad = (const float*)d_in[2];  // atomic_quadrupoles  [N,3,3]
    const float* vec  = (const float*)d_in[3];  // vectors_uv          [E,3]
    const float* dist = (const float*)d_in[4];  // distances_uv        [E]
    const int*   iu   = (const int*)d_in[5];    // idx_u               [E]
    const int*   iv   = (const int*)d_in[6];    // idx_v               [E]
    float* out = (float*)d_out;

    int N = in_sizes[0];
    int E = in_sizes[4];
    int block = 256;
    int egrid = (E + block - 1) / block;

    size_t need = (size_t)N * 64;
    if (ws_size >= need) {
        float* packed = (float*)d_ws;
        int pgrid = (N + block - 1) / block;
        pack_atoms_kernel<<<pgrid, block, 0, stream>>>(q, dip, quad, packed, N);
        damped_elec_packed<<<egrid, block, 0, stream>>>(packed, vec, dist, iu, iv, out, E);
    } else {
        damped_elec_unpacked<<<egrid, block, 0, stream>>>(q, dip, quad, vec, dist, iu, iv, out, E);
    }
}

// Round 5
// 75.345 us; speedup vs baseline: 1.4527x; 1.1020x over previous
//
#include <hip/hip_runtime.h>

// Damped electrostatics with shifted-force cutoff.
// Two packed atom tables in d_ws:
//   A [N]  : (q, dip.x, dip.y, dip.z)                  16B -> 1.6 MB, L2-resident
//   B [N]  : (s00,s11,s22,trQ/3 | d01,d02,d12,pad)     32B -> 3.2 MB
// (only the symmetric part of Q enters v^T Q v). Streams are non-temporal
// so they don't evict the tables from the per-XCD L2.

#define CUTOFF      10.0f
#define KEHALF      7.199822675975274f
#define OFFSET2     1.0f

typedef float f32x4 __attribute__((ext_vector_type(4)));

__global__ __launch_bounds__(256) void pack_atoms_kernel(
    const float* __restrict__ q,
    const float* __restrict__ dip,
    const float* __restrict__ quad,
    float* __restrict__ tabA,   // [N,4]
    float* __restrict__ tabB,   // [N,8]
    int N)
{
    int i = blockIdx.x * blockDim.x + threadIdx.x;
    if (i >= N) return;
    const float* dp = dip + 3 * (size_t)i;
    const float* qp = quad + 9 * (size_t)i;
    f32x4 a = {q[i], dp[0], dp[1], dp[2]};
    ((f32x4*)tabA)[i] = a;

    float q00 = qp[0], q01 = qp[1], q02 = qp[2];
    float q10 = qp[3], q11 = qp[4], q12 = qp[5];
    float q20 = qp[6], q21 = qp[7], q22 = qp[8];
    f32x4 b0 = {q00, q11, q22, (q00 + q11 + q22) * (1.0f / 3.0f)};
    f32x4 b1 = {q01 + q10, q02 + q20, q12 + q21, 0.0f};
    ((f32x4*)tabB)[2 * (size_t)i + 0] = b0;
    ((f32x4*)tabB)[2 * (size_t)i + 1] = b1;
}

__global__ __launch_bounds__(256) void damped_elec_split(
    const float* __restrict__ tabA,   // [N,4]
    const float* __restrict__ tabB,   // [N,8]
    const float* __restrict__ vec,    // [E,3]
    const float* __restrict__ dist,   // [E]
    const int*   __restrict__ idx_u,  // [E]
    const int*   __restrict__ idx_v,  // [E]
    float*       __restrict__ out,    // [E]
    int E)
{
    int i = blockIdx.x * blockDim.x + threadIdx.x;
    if (i >= E) return;

    // streaming loads (non-temporal: keep L2 for the tables)
    int u = __builtin_nontemporal_load(idx_u + i);
    int v = __builtin_nontemporal_load(idx_v + i);
    float d  = __builtin_nontemporal_load(dist + i);
    float vx = __builtin_nontemporal_load(vec + 3 * (size_t)i + 0);
    float vy = __builtin_nontemporal_load(vec + 3 * (size_t)i + 1);
    float vz = __builtin_nontemporal_load(vec + 3 * (size_t)i + 2);

    // gathers (L2-resident tables)
    f32x4 au = ((const f32x4*)tabA)[(size_t)u];
    f32x4 av = ((const f32x4*)tabA)[(size_t)v];
    f32x4 b0 = ((const f32x4*)tabB)[2 * (size_t)v + 0];
    f32x4 b1 = ((const f32x4*)tabB)[2 * (size_t)v + 1];

    float qu = au.x, du0 = au.y, du1 = au.z, du2 = au.w;
    float qv = av.x, dv0 = av.y, dv1 = av.z, dv2 = av.w;

    float inv_d = 1.0f / d;
    float d_damped = sqrtf(d * d + OFFSET2);

    // poly5 switch, cutoff_sr = 4
    float x = d * 0.25f;
    float x2 = x * x;
    float x3 = x2 * x;
    float sw = 1.0f - x3 * (10.0f - 15.0f * x + 6.0f * x2);
    sw = (x < 1.0f) ? sw : 0.0f;
    float chi = sw / d_damped + (1.0f - sw) * inv_d;

    // shifted-force corrections (cutoff = 10)
    float c1 = chi - (0.2f   - 0.01f   * d);
    float chi2 = chi * chi;
    float chi3 = chi2 * chi;
    float c2 = chi2 - (0.03f  - 0.002f  * d);
    float c3 = chi3 - (0.004f - 0.0003f * d);

    float Ee = qu * qv * c1;

    float dot_uv = (vx * dv0 + vy * dv1 + vz * dv2) * inv_d;
    float dot_vu = (vx * du0 + vy * du1 + vz * du2) * inv_d;
    float dd     = du0 * dv0 + du1 * dv1 + du2 * dv2;

    Ee += 2.0f * qu * dot_uv * c2;
    Ee += (dd - 3.0f * dot_uv * dot_vu) * c3;

    // quadrupole via symmetric components:
    // vQv = s00 vx^2 + s11 vy^2 + s22 vz^2 + d01 vx vy + d02 vx vz + d12 vy vz
    float vQv = b0.x * vx * vx + b0.y * vy * vy + b0.z * vz * vz
              + b1.x * vx * vy + b1.y * vx * vz + b1.z * vy * vz;
    float sum_uv = vQv * inv_d * inv_d - b0.w;   // b0.w = trQ/3

    Ee += qu * sum_uv * c3;

    Ee *= KEHALF;
    float r = (d <= CUTOFF) ? Ee : 0.0f;
    __builtin_nontemporal_store(r, out + i);
}

// Fallback if ws_size is too small for the packed tables.
__global__ __launch_bounds__(256) void damped_elec_unpacked(
    const float* __restrict__ q,
    const float* __restrict__ dip,
    const float* __restrict__ quad,
    const float* __restrict__ vec,
    const float* __restrict__ dist,
    const int*   __restrict__ idx_u,
    const int*   __restrict__ idx_v,
    float*       __restrict__ out,
    int E)
{
    int i = blockIdx.x * blockDim.x + threadIdx.x;
    if (i >= E) return;
    float d  = dist[i];
    float vx = vec[3 * (size_t)i + 0];
    float vy = vec[3 * (size_t)i + 1];
    float vz = vec[3 * (size_t)i + 2];
    int u = idx_u[i];
    int v = idx_v[i];
    const float* pu = dip + 3 * (size_t)u;
    const float* pv = dip + 3 * (size_t)v;
    const float* pq = quad + 9 * (size_t)v;

    float qu = q[u], qv = q[v];
    float du0 = pu[0], du1 = pu[1], du2 = pu[2];
    float dv0 = pv[0], dv1 = pv[1], dv2 = pv[2];

    float inv_d = 1.0f / d;
    float d_damped = sqrtf(d * d + OFFSET2);
    float x = d * 0.25f;
    float x2 = x * x;
    float x3 = x2 * x;
    float sw = 1.0f - x3 * (10.0f - 15.0f * x + 6.0f * x2);
    sw = (x < 1.0f) ? sw : 0.0f;
    float chi = sw / d_damped + (1.0f - sw) * inv_d;
    float c1 = chi - (0.2f   - 0.01f   * d);
    float chi2 = chi * chi;
    float chi3 = chi2 * chi;
    float c2 = chi2 - (0.03f  - 0.002f  * d);
    float c3 = chi3 - (0.004f - 0.0003f * d);

    float Ee = qu * qv * c1;
    float dot_uv = (vx * dv0 + vy * dv1 + vz * dv2) * inv_d;
    float dot_vu = (vx * du0 + vy * du1 + vz * du2) * inv_d;
    float dd     = du0 * dv0 + du1 * dv1 + du2 * dv2;
    Ee += 2.0f * qu * dot_uv * c2;
    Ee += (dd - 3.0f * dot_uv * dot_vu) * c3;

    float vQv = vx * (pq[0] * vx + pq[1] * vy + pq[2] * vz)
              + vy * (pq[3] * vx + pq[4] * vy + pq[5] * vz)
              + vz * (pq[6] * vx + pq[7] * vy + pq[8] * vz);
    float trQ = pq[0] + pq[4] + pq[8];
    float sum_uv = vQv * inv_d * inv_d - trQ * (1.0f / 3.0f);
    Ee += qu * sum_uv * c3;

    Ee *= KEHALF;
    out[i] = (d <= CUTOFF) ? Ee : 0.0f;
}

extern "C" void kernel_launch(void* const* d_in, const int* in_sizes, int n_in,
                              void* d_out, int out_size, void* d_ws, size_t ws_size,
                              hipStream_t stream) {
    const float* q    = (const float*)d_in[0];  // atomic_charges      [N]
    const float* dip  = (const float*)d_in[1];  // atomic_dipoles      [N,3]
    const float* quad = (const float*)d_in[2];  // atomic_quadrupoles  [N,3,3]
    const float* vec  = (const float*)d_in[3];  // vectors_uv          [E,3]
    const float* dist = (const float*)d_in[4];  // distances_uv        [E]
    const int*   iu   = (const int*)d_in[5];    // idx_u               [E]
    const int*   iv   = (const int*)d_in[6];    // idx_v               [E]
    float* out = (float*)d_out;

    int N = in_sizes[0];
    int E = in_sizes[4];
    int block = 256;
    int egrid = (E + block - 1) / block;

    size_t needA = (size_t)N * 16;
    size_t needB = (size_t)N * 32;
    if (ws_size >= needA + needB) {
        float* tabA = (float*)d_ws;
        float* tabB = (float*)((char*)d_ws + needA);
        int pgrid = (N + block - 1) / block;
        pack_atoms_kernel<<<pgrid, block, 0, stream>>>(q, dip, quad, tabA, tabB, N);
        damped_elec_split<<<egrid, block, 0, stream>>>(tabA, tabB, vec, dist, iu, iv, out, E);
    } else {
        damped_elec_unpacked<<<egrid, block, 0, stream>>>(q, dip, quad, vec, dist, iu, iv, out, E);
    }
}